// Round 2
// baseline (12728.875 us; speedup 1.0000x reference)
//
#include <hip/hip_runtime.h>
#include <math.h>

// Problem dims
#define NBATCH 32
#define NPOS   1024
#define NTOK   32768          // NBATCH*NPOS
#define DMODEL 512
#define NHEAD  8
#define DHD    64
#define NROWS  262144         // NTOK*NHEAD
#define MMR    266            // random-feature count
#define NDFF   2048
#define NEXP   4
#define CIN    128            // PL*CIN = flattened patch dim

#define DNSC   0.35355339059327373f   // 64^-0.25
#define RSM    0.06131393394849658f   // 266^-0.5
#define NEG_INF -3.0e38f

// ---------------- workspace layout (float offsets), total 21,664,288 floats = 86.7 MB ----
static const size_t F_BUF1 = 0;          // 16777216 (K -> Q -> pre -> Z)
static const size_t F_CTX  = 16777216;   // 4358144 (256*266*64)
static const size_t F_KSUM = 21135360;   // 68096 (256*266)
static const size_t F_PART = 21203456;   // 2048
static const size_t F_STAB = 21205504;   // 16
static const size_t F_EFF  = 21205520;   // 3*512*128 = 196608
static const size_t F_CNTI = 21402128;   // 16 (ints)
static const size_t F_TOKI = 21402144;   // 4*32768 ints
static const size_t F_GWF  = 21533216;   // 4*32768 floats
static const size_t F_END  = 21664288;

// ---------------- fallback (ws too small): write zeros, fail cleanly, no fault -----------
__global__ __launch_bounds__(256) void fallback_zero_kernel(float* __restrict__ out) {
  out[(size_t)blockIdx.x * 256 + threadIdx.x] = 0.f;
}

// ---------------- effective QKV matrices: eff[mat] = W[mat] @ emb_w  (512x128) ----------
__global__ __launch_bounds__(128) void effmat_kernel(
    const float* __restrict__ wq, const float* __restrict__ wk, const float* __restrict__ wv,
    const float* __restrict__ emb, float* __restrict__ eff)
{
  __shared__ float wrow[512];
  const int bid = blockIdx.x;          // 0..1535
  const int mat = bid >> 9;
  const int n   = bid & 511;
  const float* W = (mat == 0) ? wq : ((mat == 1) ? wk : wv);
  const int tid = threadIdx.x;         // 128
  for (int i = tid; i < 512; i += 128) wrow[i] = W[n * 512 + i];
  __syncthreads();
  float acc = 0.f;
  for (int d = 0; d < 512; ++d) acc += wrow[d] * emb[d * CIN + tid];
  eff[mat * 65536 + n * CIN + tid] = acc;
}

// ---------------- helpers ----------------
// Stage proj (266x64) into LDS padded to 272 rows x 68 cols (zero padded).
__device__ __forceinline__ void stage_proj(float* pj, const float* __restrict__ proj, int tid) {
  for (int idx = tid; idx < 272 * 68; idx += 256) pj[idx] = 0.f;
  __syncthreads();
  for (int idx = tid; idx < MMR * 64; idx += 256) {
    int m = idx >> 6, d = idx & 63;
    pj[m * 68 + d] = proj[idx];
  }
}

// ------- generic GEMM: C = A(MxK)*W(NxK)^T [+ A2(MxK2)*W2(NxK2)^T] + bias --------------
__global__ __launch_bounds__(256) void gemm_nt_kernel(
    const float* __restrict__ A, const float* __restrict__ W, int K,
    const float* __restrict__ A2, const float* __restrict__ W2, int K2,
    const float* __restrict__ bias, float* __restrict__ C, int N, int ncb)
{
  __shared__ float As[32][64];
  __shared__ float Ws[32][64];
  const int tid  = threadIdx.x;
  const int bx   = blockIdx.x % ncb;
  const int by   = blockIdx.x / ncb;
  const int row0 = by * 64, col0 = bx * 64;
  const int tx   = tid & 15, ty = tid >> 4;
  const int lr   = tid >> 3;
  const int lk   = (tid & 7) * 4;
  float acc[4][4] = {};
  for (int pass = 0; pass < 2; ++pass) {
    const float* Ap = pass ? A2 : A;
    const float* Wp = pass ? W2 : W;
    const int    Kp = pass ? K2 : K;
    if (!Ap) continue;
    for (int k0 = 0; k0 < Kp; k0 += 32) {
      __syncthreads();
#pragma unroll
      for (int rr = 0; rr < 2; ++rr) {
        const int r = lr + rr * 32;
        float4 a4 = *(const float4*)&Ap[(size_t)(row0 + r) * Kp + k0 + lk];
        As[lk + 0][r] = a4.x; As[lk + 1][r] = a4.y; As[lk + 2][r] = a4.z; As[lk + 3][r] = a4.w;
        float4 w4 = *(const float4*)&Wp[(size_t)(col0 + r) * Kp + k0 + lk];
        Ws[lk + 0][r] = w4.x; Ws[lk + 1][r] = w4.y; Ws[lk + 2][r] = w4.z; Ws[lk + 3][r] = w4.w;
      }
      __syncthreads();
#pragma unroll
      for (int kk = 0; kk < 32; ++kk) {
        float4 av = *(const float4*)&As[kk][ty * 4];
        float4 wv = *(const float4*)&Ws[kk][tx * 4];
        acc[0][0] += av.x * wv.x; acc[0][1] += av.x * wv.y; acc[0][2] += av.x * wv.z; acc[0][3] += av.x * wv.w;
        acc[1][0] += av.y * wv.x; acc[1][1] += av.y * wv.y; acc[1][2] += av.y * wv.z; acc[1][3] += av.y * wv.w;
        acc[2][0] += av.z * wv.x; acc[2][1] += av.z * wv.y; acc[2][2] += av.z * wv.z; acc[2][3] += av.z * wv.w;
        acc[3][0] += av.w * wv.x; acc[3][1] += av.w * wv.y; acc[3][2] += av.w * wv.z; acc[3][3] += av.w * wv.w;
      }
    }
  }
#pragma unroll
  for (int i = 0; i < 4; ++i) {
    const int row = row0 + ty * 4 + i;
    const int col = col0 + tx * 4;
    float4 o = make_float4(acc[i][0], acc[i][1], acc[i][2], acc[i][3]);
    if (bias) {
      float4 b4 = *(const float4*)&bias[col];
      o.x += b4.x; o.y += b4.y; o.z += b4.z; o.w += b4.w;
    }
    *(float4*)&C[(size_t)row * N + col] = o;
  }
}

// ---------------- global max of k-dash (for key stabilizer) ----------------
__global__ __launch_bounds__(256) void kdash_max_kernel(
    const float* __restrict__ Kbuf, const float* __restrict__ proj, float* __restrict__ partial)
{
  __shared__ float pj[272 * 68];
  __shared__ float kl[32 * 68];
  __shared__ float red[256];
  const int tid = threadIdx.x;
  stage_proj(pj, proj, tid);
  const int i8 = tid >> 3, ml = tid & 7, mb = ml * 34;
  const size_t rid0 = (size_t)blockIdx.x * 128;
  float mx = NEG_INF;
  for (int ch = 0; ch < 4; ++ch) {
    __syncthreads();
    for (int idx = tid; idx < 2048; idx += 256) {
      int r = idx >> 6, dd = idx & 63;
      kl[r * 68 + dd] = Kbuf[(rid0 + ch * 32 + r) * 64 + dd] * DNSC;
    }
    __syncthreads();
    float dacc[34];
#pragma unroll
    for (int j = 0; j < 34; ++j) dacc[j] = 0.f;
    for (int d0 = 0; d0 < 64; d0 += 4) {
      float4 k4 = *(const float4*)&kl[i8 * 68 + d0];
#pragma unroll
      for (int j = 0; j < 34; ++j) {
        float4 p4 = *(const float4*)&pj[(mb + j) * 68 + d0];
        dacc[j] += k4.x * p4.x + k4.y * p4.y + k4.z * p4.z + k4.w * p4.w;
      }
    }
#pragma unroll
    for (int j = 0; j < 34; ++j) {
      int m = mb + j;
      mx = fmaxf(mx, (m < MMR) ? dacc[j] : NEG_INF);
    }
  }
  red[tid] = mx;
  __syncthreads();
  for (int st = 128; st > 0; st >>= 1) {
    if (tid < st) red[tid] = fmaxf(red[tid], red[tid + st]);
    __syncthreads();
  }
  if (tid == 0) partial[blockIdx.x] = red[0];
}

__global__ __launch_bounds__(256) void reduce_max_kernel(
    const float* __restrict__ part, float* __restrict__ stab, int n)
{
  __shared__ float red[256];
  float m = NEG_INF;
  for (int i = threadIdx.x; i < n; i += 256) m = fmaxf(m, part[i]);
  red[threadIdx.x] = m;
  __syncthreads();
  for (int st = 128; st > 0; st >>= 1) {
    if (threadIdx.x < st) red[threadIdx.x] = fmaxf(red[threadIdx.x], red[threadIdx.x + st]);
    __syncthreads();
  }
  if (threadIdx.x == 0) stab[0] = red[0];
}

// ---------------- ctx = kp^T @ v, ksum = sum_n kp  (one block per (b,h)) ----------------
__global__ __launch_bounds__(256) void ctx_kernel(
    const float* __restrict__ Kbuf, const float* __restrict__ Vbuf,
    const float* __restrict__ proj, const float* __restrict__ stabp,
    float* __restrict__ ctxg, float* __restrict__ ksumg)
{
  __shared__ float pj[272 * 68];
  __shared__ float kl[32 * 68];
  __shared__ float vl[32 * 68];
  __shared__ float kp[32 * 272];
  __shared__ float ks[272];
  const int tid = threadIdx.x;
  const int bh = blockIdx.x;
  const int b = bh >> 3, h = bh & 7;
  const float stab = stabp[0];
  stage_proj(pj, proj, tid);
  for (int m = tid; m < 272; m += 256) ks[m] = 0.f;
  const int d = tid & 63, mg = tid >> 6;
  const int i8 = tid >> 3, ml = tid & 7, mb = ml * 34;
  float acc[68];
#pragma unroll
  for (int jj = 0; jj < 68; ++jj) acc[jj] = 0.f;
  for (int n0 = 0; n0 < NPOS; n0 += 32) {
    __syncthreads();
    for (int idx = tid; idx < 2048; idx += 256) {
      int r = idx >> 6, dd = idx & 63;
      size_t g = ((size_t)(b * NPOS + n0 + r)) * DMODEL + h * DHD + dd;
      kl[r * 68 + dd] = Kbuf[g] * DNSC;
      vl[r * 68 + dd] = Vbuf[g];
    }
    __syncthreads();
    float dacc[34];
#pragma unroll
    for (int j = 0; j < 34; ++j) dacc[j] = 0.f;
    float diag = 0.f;
    for (int d0 = 0; d0 < 64; d0 += 4) {
      float4 k4 = *(const float4*)&kl[i8 * 68 + d0];
      diag += k4.x * k4.x + k4.y * k4.y + k4.z * k4.z + k4.w * k4.w;
#pragma unroll
      for (int j = 0; j < 34; ++j) {
        float4 p4 = *(const float4*)&pj[(mb + j) * 68 + d0];
        dacc[j] += k4.x * p4.x + k4.y * p4.y + k4.z * p4.z + k4.w * p4.w;
      }
    }
    diag *= 0.5f;
#pragma unroll
    for (int j = 0; j < 34; ++j) {
      int m = mb + j;
      if (m < MMR) kp[i8 * 272 + m] = RSM * (expf(dacc[j] - diag - stab) + 1e-4f);
    }
    if (ml < 6) kp[i8 * 272 + MMR + ml] = 0.f;
    __syncthreads();
    for (int m = tid; m < MMR; m += 256) {
      float s = 0.f;
#pragma unroll 8
      for (int i = 0; i < 32; ++i) s += kp[i * 272 + m];
      ks[m] += s;
    }
    for (int i = 0; i < 32; ++i) {
      const float vv = vl[i * 68 + d];
      const float* kr = &kp[i * 272 + mg * 68];
#pragma unroll
      for (int jj = 0; jj < 17; ++jj) {
        float4 k4 = *(const float4*)&kr[jj * 4];
        acc[4 * jj + 0] += k4.x * vv;
        acc[4 * jj + 1] += k4.y * vv;
        acc[4 * jj + 2] += k4.z * vv;
        acc[4 * jj + 3] += k4.w * vv;
      }
    }
  }
  const size_t cb = (size_t)bh * MMR * DHD;
#pragma unroll
  for (int jj = 0; jj < 68; ++jj) {
    int m = mg * 68 + jj;
    if (m < MMR) ctxg[cb + (size_t)m * 64 + d] = acc[jj];
  }
  for (int m = tid; m < MMR; m += 256) ksumg[bh * MMR + m] = ks[m];
}

// ---------------- attn = (qp @ ctx)/den  (block = (b,h) x 32 query rows) ----------------
__global__ __launch_bounds__(256) void attn_kernel(
    const float* __restrict__ Qbuf, const float* __restrict__ ctxg,
    const float* __restrict__ ksumg, const float* __restrict__ proj,
    float* __restrict__ attnb)
{
  __shared__ float pj[272 * 68];
  __shared__ float ql[32 * 68];
  __shared__ float qp[32 * 272];
  __shared__ float ks[272];
  __shared__ float den_s[32];
  const int tid = threadIdx.x;
  const int bh = blockIdx.x >> 5;
  const int nc = blockIdx.x & 31;
  const int b = bh >> 3, h = bh & 7;
  const int n0 = nc * 32;
  stage_proj(pj, proj, tid);
  for (int m = tid; m < 272; m += 256) ks[m] = (m < MMR) ? ksumg[bh * MMR + m] : 0.f;
  for (int idx = tid; idx < 2048; idx += 256) {
    int r = idx >> 6, dd = idx & 63;
    ql[r * 68 + dd] = Qbuf[((size_t)(b * NPOS + n0 + r)) * DMODEL + h * DHD + dd] * DNSC;
  }
  __syncthreads();
  const int i8 = tid >> 3, ml = tid & 7, mb = ml * 34;
  float dacc[34];
#pragma unroll
  for (int j = 0; j < 34; ++j) dacc[j] = 0.f;
  float diag = 0.f;
  for (int d0 = 0; d0 < 64; d0 += 4) {
    float4 k4 = *(const float4*)&ql[i8 * 68 + d0];
    diag += k4.x * k4.x + k4.y * k4.y + k4.z * k4.z + k4.w * k4.w;
#pragma unroll
    for (int j = 0; j < 34; ++j) {
      float4 p4 = *(const float4*)&pj[(mb + j) * 68 + d0];
      dacc[j] += k4.x * p4.x + k4.y * p4.y + k4.z * p4.z + k4.w * p4.w;
    }
  }
  diag *= 0.5f;
  float mx = NEG_INF;
#pragma unroll
  for (int j = 0; j < 34; ++j) {
    int m = mb + j;
    mx = fmaxf(mx, (m < MMR) ? dacc[j] : NEG_INF);
  }
#pragma unroll
  for (int off = 1; off < 8; off <<= 1) mx = fmaxf(mx, __shfl_xor(mx, off));
  float dp = 0.f;
#pragma unroll
  for (int j = 0; j < 34; ++j) {
    int m = mb + j;
    if (m < MMR) {
      float v = RSM * (expf(dacc[j] - diag - mx) + 1e-4f);
      qp[i8 * 272 + m] = v;
      dp += v * ks[m];
    }
  }
  if (ml < 6) qp[i8 * 272 + MMR + ml] = 0.f;
#pragma unroll
  for (int off = 1; off < 8; off <<= 1) dp += __shfl_xor(dp, off);
  if (ml == 0) den_s[i8] = dp;
  __syncthreads();
  const int lane = tid & 63, wid = tid >> 6;
  float acc[8];
#pragma unroll
  for (int t = 0; t < 8; ++t) acc[t] = 0.f;
  const float* cb = ctxg + (size_t)bh * MMR * DHD + lane;
  for (int m0 = 0; m0 < 264; m0 += 4) {
    float c0 = cb[(size_t)(m0 + 0) * 64];
    float c1 = cb[(size_t)(m0 + 1) * 64];
    float c2 = cb[(size_t)(m0 + 2) * 64];
    float c3 = cb[(size_t)(m0 + 3) * 64];
#pragma unroll
    for (int t = 0; t < 8; ++t) {
      float4 q4 = *(const float4*)&qp[(wid + 4 * t) * 272 + m0];
      acc[t] += q4.x * c0 + q4.y * c1 + q4.z * c2 + q4.w * c3;
    }
  }
  {
    float c0 = cb[264 * 64], c1 = cb[265 * 64];
#pragma unroll
    for (int t = 0; t < 8; ++t)
      acc[t] += qp[(wid + 4 * t) * 272 + 264] * c0 + qp[(wid + 4 * t) * 272 + 265] * c1;
  }
#pragma unroll
  for (int t = 0; t < 8; ++t) {
    int r = wid + 4 * t;
    size_t o = ((size_t)(b * NPOS + n0 + r)) * DMODEL + h * DHD + lane;
    attnb[o] = acc[t] / den_s[r];
  }
}

// ---------------- LayerNorm (one block per row); optional second output ----------------
__global__ __launch_bounds__(256) void ln_kernel(
    const float* __restrict__ in, const float* __restrict__ g, const float* __restrict__ bb,
    float* __restrict__ out, float* __restrict__ out2)
{
  const int row = blockIdx.x, tid = threadIdx.x;
  float2 x = *(const float2*)&in[(size_t)row * DMODEL + tid * 2];
  float s = x.x + x.y, sq = x.x * x.x + x.y * x.y;
#pragma unroll
  for (int off = 32; off > 0; off >>= 1) {
    s += __shfl_down(s, off);
    sq += __shfl_down(sq, off);
  }
  __shared__ float ps[4], pq[4];
  __shared__ float smu, srv;
  const int wv = tid >> 6, ln = tid & 63;
  if (ln == 0) { ps[wv] = s; pq[wv] = sq; }
  __syncthreads();
  if (tid == 0) {
    float S = ps[0] + ps[1] + ps[2] + ps[3];
    float Q = pq[0] + pq[1] + pq[2] + pq[3];
    float mu = S / 512.f;
    float var = Q / 512.f - mu * mu;
    smu = mu;
    srv = 1.0f / sqrtf(var + 1e-5f);
  }
  __syncthreads();
  const float mu = smu, rv = srv;
  const int c = tid * 2;
  float y0 = (x.x - mu) * rv * g[c] + bb[c];
  float y1 = (x.y - mu) * rv * g[c + 1] + bb[c + 1];
  out[(size_t)row * DMODEL + c] = y0;
  out[(size_t)row * DMODEL + c + 1] = y1;
  if (out2) {
    out2[(size_t)row * DMODEL + c] = y0;
    out2[(size_t)row * DMODEL + c + 1] = y1;
  }
}

// ---------------- gating: logits -> top2 -> softmax -> expert lists ----------------
__global__ __launch_bounds__(64) void zero_cnt_kernel(int* __restrict__ cnt)
{
  if (threadIdx.x < NEXP) cnt[threadIdx.x] = 0;
}

__global__ __launch_bounds__(256) void gate_kernel(
    const float* __restrict__ h1, const float* __restrict__ gw, const float* __restrict__ gb,
    int* __restrict__ cnt, int* __restrict__ toks, float* __restrict__ gws)
{
  const int wv = threadIdx.x >> 6, ln = threadIdx.x & 63;
  const int tok = blockIdx.x * 4 + wv;
  const float* hr = h1 + (size_t)tok * DMODEL;
  float p0 = 0, p1 = 0, p2 = 0, p3 = 0;
#pragma unroll
  for (int k = 0; k < 8; ++k) {
    float xv = hr[ln + 64 * k];
    p0 += xv * gw[0 * DMODEL + ln + 64 * k];
    p1 += xv * gw[1 * DMODEL + ln + 64 * k];
    p2 += xv * gw[2 * DMODEL + ln + 64 * k];
    p3 += xv * gw[3 * DMODEL + ln + 64 * k];
  }
#pragma unroll
  for (int off = 32; off > 0; off >>= 1) {
    p0 += __shfl_down(p0, off);
    p1 += __shfl_down(p1, off);
    p2 += __shfl_down(p2, off);
    p3 += __shfl_down(p3, off);
  }
  if (ln == 0) {
    p0 += gb[0]; p1 += gb[1]; p2 += gb[2]; p3 += gb[3];
    int i0 = 0; float v0 = p0;
    if (p1 > v0) { v0 = p1; i0 = 1; }
    if (p2 > v0) { v0 = p2; i0 = 2; }
    if (p3 > v0) { v0 = p3; i0 = 3; }
    int i1 = -1; float v1 = NEG_INF;
    if (i0 != 0 && p0 > v1) { v1 = p0; i1 = 0; }
    if (i0 != 1 && p1 > v1) { v1 = p1; i1 = 1; }
    if (i0 != 2 && p2 > v1) { v1 = p2; i1 = 2; }
    if (i0 != 3 && p3 > v1) { v1 = p3; i1 = 3; }
    float e = expf(v1 - v0);
    float w0 = 1.f / (1.f + e);
    float w1 = e / (1.f + e);
    int pos0 = atomicAdd(&cnt[i0], 1);
    toks[i0 * NTOK + pos0] = tok;
    gws[i0 * NTOK + pos0] = w0;
    int pos1 = atomicAdd(&cnt[i1], 1);
    toks[i1 * NTOK + pos1] = tok;
    gws[i1 * NTOK + pos1] = w1;
  }
}

// ---------------- grouped MoE: fused (relu(t@w1+b1))@w2+b2, weighted scatter ----------------
__global__ __launch_bounds__(256) void moe_kernel(
    const float* __restrict__ h1, const float* __restrict__ w1, const float* __restrict__ b1,
    const float* __restrict__ w2, const float* __restrict__ b2,
    const int* __restrict__ cnt, const int* __restrict__ toks, const float* __restrict__ gws,
    float* __restrict__ Z)
{
  __shared__ float t_lds[32 * DMODEL];
  __shared__ float h_lds[32 * 65];
  __shared__ int tk_s[32];
  __shared__ float gw_s[32];
  const int tid = threadIdx.x;
  const int e = blockIdx.x >> 10;
  const int tile = blockIdx.x & 1023;
  const int cn = cnt[e];
  if (tile * 32 >= cn) return;
  if (tid < 32) {
    int idx = tile * 32 + tid;
    if (idx < cn) { tk_s[tid] = toks[e * NTOK + idx]; gw_s[tid] = gws[e * NTOK + idx]; }
    else          { tk_s[tid] = -1;                  gw_s[tid] = 0.f; }
  }
  __syncthreads();
  for (int it = tid; it < 32 * 128; it += 256) {
    int r = it >> 7, c4 = (it & 127) * 4;
    int tk = tk_s[r];
    float4 v = make_float4(0.f, 0.f, 0.f, 0.f);
    if (tk >= 0) v = *(const float4*)&h1[(size_t)tk * DMODEL + c4];
    *(float4*)&t_lds[r * DMODEL + c4] = v;
  }
  const int lane = tid & 63, wid = tid >> 6;
  float yacc[8][8];
#pragma unroll
  for (int t = 0; t < 8; ++t)
#pragma unroll
    for (int u = 0; u < 8; ++u) yacc[t][u] = 0.f;
  __syncthreads();
  const float* w1p = w1 + (size_t)e * DMODEL * NDFF;
  const float* w2p = w2 + (size_t)e * NDFF * DMODEL;
  for (int f0 = 0; f0 < NDFF; f0 += 64) {
    float hacc[8];
#pragma unroll
    for (int t = 0; t < 8; ++t) hacc[t] = 0.f;
    const float* w1c = w1p + f0 + lane;
    for (int d0 = 0; d0 < DMODEL; d0 += 4) {
      float wa = w1c[(size_t)(d0 + 0) * NDFF];
      float wb = w1c[(size_t)(d0 + 1) * NDFF];
      float wc = w1c[(size_t)(d0 + 2) * NDFF];
      float wd = w1c[(size_t)(d0 + 3) * NDFF];
#pragma unroll
      for (int t = 0; t < 8; ++t) {
        float4 tv = *(const float4*)&t_lds[(wid + 4 * t) * DMODEL + d0];
        hacc[t] += tv.x * wa + tv.y * wb + tv.z * wc + tv.w * wd;
      }
    }
    float bb = b1[e * NDFF + f0 + lane];
#pragma unroll
    for (int t = 0; t < 8; ++t) h_lds[(wid + 4 * t) * 65 + lane] = fmaxf(hacc[t] + bb, 0.f);
    __syncthreads();
    const float* w2c = w2p + (size_t)f0 * DMODEL + lane;
    for (int f = 0; f < 64; ++f) {
      float w2v[8];
#pragma unroll
      for (int u = 0; u < 8; ++u) w2v[u] = w2c[(size_t)f * DMODEL + 64 * u];
#pragma unroll
      for (int t = 0; t < 8; ++t) {
        float hv = h_lds[(wid + 4 * t) * 65 + f];
#pragma unroll
        for (int u = 0; u < 8; ++u) yacc[t][u] += hv * w2v[u];
      }
    }
    __syncthreads();
  }
  float b2v[8];
#pragma unroll
  for (int u = 0; u < 8; ++u) b2v[u] = b2[e * DMODEL + lane + 64 * u];
#pragma unroll
  for (int t = 0; t < 8; ++t) {
    int r = wid + 4 * t;
    int tk = tk_s[r];
    if (tk >= 0) {
      float gv = gw_s[r];
#pragma unroll
      for (int u = 0; u < 8; ++u)
        atomicAdd(&Z[(size_t)tk * DMODEL + lane + 64 * u], (yacc[t][u] + b2v[u]) * gv);
    }
  }
}

// ---------------- launch ----------------
extern "C" void kernel_launch(void* const* d_in, const int* in_sizes, int n_in,
                              void* d_out, int out_size, void* d_ws, size_t ws_size,
                              hipStream_t stream) {
  const float* x     = (const float*)d_in[0];
  const float* emb_w = (const float*)d_in[1];
  const float* wq    = (const float*)d_in[2];
  const float* bq    = (const float*)d_in[3];
  const float* wk    = (const float*)d_in[4];
  const float* bk    = (const float*)d_in[5];
  const float* wv    = (const float*)d_in[6];
  const float* bv    = (const float*)d_in[7];
  const float* wo    = (const float*)d_in[8];
  const float* bo    = (const float*)d_in[9];
  const float* proj  = (const float*)d_in[10];
  const float* ln2g  = (const float*)d_in[11];
  const float* ln2b  = (const float*)d_in[12];
  const float* ln3g  = (const float*)d_in[13];
  const float* ln3b  = (const float*)d_in[14];
  const float* gatew = (const float*)d_in[15];
  const float* gateb = (const float*)d_in[16];
  const float* w1    = (const float*)d_in[17];
  const float* b1    = (const float*)d_in[18];
  const float* w2    = (const float*)d_in[19];
  const float* b2    = (const float*)d_in[20];
  float* out = (float*)d_out;
  float* ws  = (float*)d_ws;

  // Guard: if workspace is too small, fail cleanly (no OOB faults).
  if (ws_size < F_END * sizeof(float)) {
    fallback_zero_kernel<<<NTOK * 2, 256, 0, stream>>>(out);
    return;
  }

  float* BUF1 = ws + F_BUF1;   // K -> Q -> pre -> Z
  float* BUF2 = out;           // V -> attn -> h1 (d_out reused as scratch)
  int*   cnt  = (int*)(ws + F_CNTI);
  int*   toks = (int*)(ws + F_TOKI);
  float* gwf  = ws + F_GWF;

  zero_cnt_kernel<<<1, 64, 0, stream>>>(cnt);
  // effective projection matrices: {wq,wk,wv} @ emb_w -> (512x128) each
  effmat_kernel<<<1536, 128, 0, stream>>>(wq, wk, wv, emb_w, ws + F_EFF);
  // K = x @ Keff^T + bk -> BUF1
  gemm_nt_kernel<<<4096, 256, 0, stream>>>(x, ws + F_EFF + 65536, CIN, nullptr, nullptr, 0, bk, BUF1, DMODEL, 8);
  // V = x @ Veff^T + bv -> BUF2 (d_out)
  gemm_nt_kernel<<<4096, 256, 0, stream>>>(x, ws + F_EFF + 131072, CIN, nullptr, nullptr, 0, bv, BUF2, DMODEL, 8);
  // global key-dash max (stabilizer)
  kdash_max_kernel<<<2048, 256, 0, stream>>>(BUF1, proj, ws + F_PART);
  reduce_max_kernel<<<1, 256, 0, stream>>>(ws + F_PART, ws + F_STAB, 2048);
  // ctx & ksum per (b,h)
  ctx_kernel<<<256, 256, 0, stream>>>(BUF1, BUF2, proj, ws + F_STAB, ws + F_CTX, ws + F_KSUM);
  // Q = x @ Qeff^T + bq -> BUF1 (K dead)
  gemm_nt_kernel<<<4096, 256, 0, stream>>>(x, ws + F_EFF, CIN, nullptr, nullptr, 0, bq, BUF1, DMODEL, 8);
  // attention output -> BUF2 (V dead)
  attn_kernel<<<8192, 256, 0, stream>>>(BUF1, ws + F_CTX, ws + F_KSUM, proj, BUF2);
  // pre = attn@wo^T + x@emb_w^T (=xe residual) + bo -> BUF1
  gemm_nt_kernel<<<4096, 256, 0, stream>>>(BUF2, wo, DMODEL, x, emb_w, CIN, bo, BUF1, DMODEL, 8);
  // h1 = LN(pre) -> BUF2; also init MoE accumulator Z = h1 -> BUF1 (in-place-safe)
  ln_kernel<<<NTOK, 256, 0, stream>>>(BUF1, ln2g, ln2b, BUF2, BUF1);
  // gating
  gate_kernel<<<8192, 256, 0, stream>>>(BUF2, gatew, gateb, cnt, toks, gwf);
  // grouped sparse MoE, scatter-add into Z (BUF1)
  moe_kernel<<<4096, 256, 0, stream>>>(BUF2, w1, b1, w2, b2, cnt, toks, gwf, BUF1);
  // final LN: reads BUF1, writes d_out
  ln_kernel<<<NTOK, 256, 0, stream>>>(BUF1, ln3g, ln3b, out, nullptr);
}

// Round 3
// 7068.316 us; speedup vs baseline: 1.8008x; 1.8008x over previous
//
#include <hip/hip_runtime.h>
#include <math.h>

// Problem dims
#define NBATCH 32
#define NPOS   1024
#define NTOK   32768          // NBATCH*NPOS
#define DMODEL 512
#define NHEAD  8
#define DHD    64
#define NROWS  262144         // NTOK*NHEAD
#define MMR    266            // random-feature count
#define NDFF   2048
#define NEXP   4
#define CIN    128            // PL*CIN = flattened patch dim

#define DNSC   0.35355339059327373f   // 64^-0.25
#define RSM    0.06131393394849658f   // 266^-0.5
#define NEG_INF -3.0e38f

typedef _Float16 half8 __attribute__((ext_vector_type(8)));
typedef float    f32x4 __attribute__((ext_vector_type(4)));

// ---------------- workspace layout (float offsets), total 21,664,288 floats = 86.7 MB ----
static const size_t F_BUF1 = 0;          // 16777216 (K -> Q -> pre -> Z)
static const size_t F_CTX  = 16777216;   // 4358144 (256*266*64); reused for fp16 weights after attn
static const size_t F_KSUM = 21135360;   // 68096 (256*266)
static const size_t F_PART = 21203456;   // 2048
static const size_t F_STAB = 21205504;   // 16
static const size_t F_EFF  = 21205520;   // 3*512*128 = 196608
static const size_t F_CNTI = 21402128;   // 16 (ints)
static const size_t F_TOKI = 21402144;   // 4*32768 ints
static const size_t F_GWF  = 21533216;   // 4*32768 floats
static const size_t F_END  = 21664288;

// ---------------- fallback (ws too small): write zeros, fail cleanly, no fault -----------
__global__ __launch_bounds__(256) void fallback_zero_kernel(float* __restrict__ out) {
  out[(size_t)blockIdx.x * 256 + threadIdx.x] = 0.f;
}

// ---------------- effective QKV matrices: eff[mat] = W[mat] @ emb_w  (512x128) ----------
__global__ __launch_bounds__(128) void effmat_kernel(
    const float* __restrict__ wq, const float* __restrict__ wk, const float* __restrict__ wv,
    const float* __restrict__ emb, float* __restrict__ eff)
{
  __shared__ float wrow[512];
  const int bid = blockIdx.x;          // 0..1535
  const int mat = bid >> 9;
  const int n   = bid & 511;
  const float* W = (mat == 0) ? wq : ((mat == 1) ? wk : wv);
  const int tid = threadIdx.x;         // 128
  for (int i = tid; i < 512; i += 128) wrow[i] = W[n * 512 + i];
  __syncthreads();
  float acc = 0.f;
  for (int d = 0; d < 512; ++d) acc += wrow[d] * emb[d * CIN + tid];
  eff[mat * 65536 + n * CIN + tid] = acc;
}

// ---------------- helpers ----------------
__device__ __forceinline__ void stage_proj(float* pj, const float* __restrict__ proj, int tid) {
  for (int idx = tid; idx < 272 * 68; idx += 256) pj[idx] = 0.f;
  __syncthreads();
  for (int idx = tid; idx < MMR * 64; idx += 256) {
    int m = idx >> 6, d = idx & 63;
    pj[m * 68 + d] = proj[idx];
  }
}

// ------- generic GEMM: C = A(MxK)*W(NxK)^T [+ A2(MxK2)*W2(NxK2)^T] + bias --------------
__global__ __launch_bounds__(256) void gemm_nt_kernel(
    const float* __restrict__ A, const float* __restrict__ W, int K,
    const float* __restrict__ A2, const float* __restrict__ W2, int K2,
    const float* __restrict__ bias, float* __restrict__ C, int N, int ncb)
{
  __shared__ float As[32][64];
  __shared__ float Ws[32][64];
  const int tid  = threadIdx.x;
  const int bx   = blockIdx.x % ncb;
  const int by   = blockIdx.x / ncb;
  const int row0 = by * 64, col0 = bx * 64;
  const int tx   = tid & 15, ty = tid >> 4;
  const int lr   = tid >> 3;
  const int lk   = (tid & 7) * 4;
  float acc[4][4] = {};
  for (int pass = 0; pass < 2; ++pass) {
    const float* Ap = pass ? A2 : A;
    const float* Wp = pass ? W2 : W;
    const int    Kp = pass ? K2 : K;
    if (!Ap) continue;
    for (int k0 = 0; k0 < Kp; k0 += 32) {
      __syncthreads();
#pragma unroll
      for (int rr = 0; rr < 2; ++rr) {
        const int r = lr + rr * 32;
        float4 a4 = *(const float4*)&Ap[(size_t)(row0 + r) * Kp + k0 + lk];
        As[lk + 0][r] = a4.x; As[lk + 1][r] = a4.y; As[lk + 2][r] = a4.z; As[lk + 3][r] = a4.w;
        float4 w4 = *(const float4*)&Wp[(size_t)(col0 + r) * Kp + k0 + lk];
        Ws[lk + 0][r] = w4.x; Ws[lk + 1][r] = w4.y; Ws[lk + 2][r] = w4.z; Ws[lk + 3][r] = w4.w;
      }
      __syncthreads();
#pragma unroll
      for (int kk = 0; kk < 32; ++kk) {
        float4 av = *(const float4*)&As[kk][ty * 4];
        float4 wv = *(const float4*)&Ws[kk][tx * 4];
        acc[0][0] += av.x * wv.x; acc[0][1] += av.x * wv.y; acc[0][2] += av.x * wv.z; acc[0][3] += av.x * wv.w;
        acc[1][0] += av.y * wv.x; acc[1][1] += av.y * wv.y; acc[1][2] += av.y * wv.z; acc[1][3] += av.y * wv.w;
        acc[2][0] += av.z * wv.x; acc[2][1] += av.z * wv.y; acc[2][2] += av.z * wv.z; acc[2][3] += av.z * wv.w;
        acc[3][0] += av.w * wv.x; acc[3][1] += av.w * wv.y; acc[3][2] += av.w * wv.z; acc[3][3] += av.w * wv.w;
      }
    }
  }
#pragma unroll
  for (int i = 0; i < 4; ++i) {
    const int row = row0 + ty * 4 + i;
    const int col = col0 + tx * 4;
    float4 o = make_float4(acc[i][0], acc[i][1], acc[i][2], acc[i][3]);
    if (bias) {
      float4 b4 = *(const float4*)&bias[col];
      o.x += b4.x; o.y += b4.y; o.z += b4.z; o.w += b4.w;
    }
    *(float4*)&C[(size_t)row * N + col] = o;
  }
}

// ---------------- global max of k-dash (for key stabilizer) ----------------
__global__ __launch_bounds__(256) void kdash_max_kernel(
    const float* __restrict__ Kbuf, const float* __restrict__ proj, float* __restrict__ partial)
{
  __shared__ float pj[272 * 68];
  __shared__ float kl[32 * 68];
  __shared__ float red[256];
  const int tid = threadIdx.x;
  stage_proj(pj, proj, tid);
  const int i8 = tid >> 3, ml = tid & 7, mb = ml * 34;
  const size_t rid0 = (size_t)blockIdx.x * 128;
  float mx = NEG_INF;
  for (int ch = 0; ch < 4; ++ch) {
    __syncthreads();
    for (int idx = tid; idx < 2048; idx += 256) {
      int r = idx >> 6, dd = idx & 63;
      kl[r * 68 + dd] = Kbuf[(rid0 + ch * 32 + r) * 64 + dd] * DNSC;
    }
    __syncthreads();
    float dacc[34];
#pragma unroll
    for (int j = 0; j < 34; ++j) dacc[j] = 0.f;
    for (int d0 = 0; d0 < 64; d0 += 4) {
      float4 k4 = *(const float4*)&kl[i8 * 68 + d0];
#pragma unroll
      for (int j = 0; j < 34; ++j) {
        float4 p4 = *(const float4*)&pj[(mb + j) * 68 + d0];
        dacc[j] += k4.x * p4.x + k4.y * p4.y + k4.z * p4.z + k4.w * p4.w;
      }
    }
#pragma unroll
    for (int j = 0; j < 34; ++j) {
      int m = mb + j;
      mx = fmaxf(mx, (m < MMR) ? dacc[j] : NEG_INF);
    }
  }
  red[tid] = mx;
  __syncthreads();
  for (int st = 128; st > 0; st >>= 1) {
    if (tid < st) red[tid] = fmaxf(red[tid], red[tid + st]);
    __syncthreads();
  }
  if (tid == 0) partial[blockIdx.x] = red[0];
}

__global__ __launch_bounds__(256) void reduce_max_kernel(
    const float* __restrict__ part, float* __restrict__ stab, int n)
{
  __shared__ float red[256];
  float m = NEG_INF;
  for (int i = threadIdx.x; i < n; i += 256) m = fmaxf(m, part[i]);
  red[threadIdx.x] = m;
  __syncthreads();
  for (int st = 128; st > 0; st >>= 1) {
    if (threadIdx.x < st) red[threadIdx.x] = fmaxf(red[threadIdx.x], red[threadIdx.x + st]);
    __syncthreads();
  }
  if (threadIdx.x == 0) stab[0] = red[0];
}

// ---------------- ctx = kp^T @ v, ksum = sum_n kp  (one block per (b,h)) ----------------
__global__ __launch_bounds__(256) void ctx_kernel(
    const float* __restrict__ Kbuf, const float* __restrict__ Vbuf,
    const float* __restrict__ proj, const float* __restrict__ stabp,
    float* __restrict__ ctxg, float* __restrict__ ksumg)
{
  __shared__ float pj[272 * 68];
  __shared__ float kl[32 * 68];
  __shared__ float vl[32 * 68];
  __shared__ float kp[32 * 272];
  __shared__ float ks[272];
  const int tid = threadIdx.x;
  const int bh = blockIdx.x;
  const int b = bh >> 3, h = bh & 7;
  const float stab = stabp[0];
  stage_proj(pj, proj, tid);
  for (int m = tid; m < 272; m += 256) ks[m] = 0.f;
  const int d = tid & 63, mg = tid >> 6;
  const int i8 = tid >> 3, ml = tid & 7, mb = ml * 34;
  float acc[68];
#pragma unroll
  for (int jj = 0; jj < 68; ++jj) acc[jj] = 0.f;
  for (int n0 = 0; n0 < NPOS; n0 += 32) {
    __syncthreads();
    for (int idx = tid; idx < 2048; idx += 256) {
      int r = idx >> 6, dd = idx & 63;
      size_t g = ((size_t)(b * NPOS + n0 + r)) * DMODEL + h * DHD + dd;
      kl[r * 68 + dd] = Kbuf[g] * DNSC;
      vl[r * 68 + dd] = Vbuf[g];
    }
    __syncthreads();
    float dacc[34];
#pragma unroll
    for (int j = 0; j < 34; ++j) dacc[j] = 0.f;
    float diag = 0.f;
    for (int d0 = 0; d0 < 64; d0 += 4) {
      float4 k4 = *(const float4*)&kl[i8 * 68 + d0];
      diag += k4.x * k4.x + k4.y * k4.y + k4.z * k4.z + k4.w * k4.w;
#pragma unroll
      for (int j = 0; j < 34; ++j) {
        float4 p4 = *(const float4*)&pj[(mb + j) * 68 + d0];
        dacc[j] += k4.x * p4.x + k4.y * p4.y + k4.z * p4.z + k4.w * p4.w;
      }
    }
    diag *= 0.5f;
#pragma unroll
    for (int j = 0; j < 34; ++j) {
      int m = mb + j;
      if (m < MMR) kp[i8 * 272 + m] = RSM * (expf(dacc[j] - diag - stab) + 1e-4f);
    }
    if (ml < 6) kp[i8 * 272 + MMR + ml] = 0.f;
    __syncthreads();
    for (int m = tid; m < MMR; m += 256) {
      float s = 0.f;
#pragma unroll 8
      for (int i = 0; i < 32; ++i) s += kp[i * 272 + m];
      ks[m] += s;
    }
    for (int i = 0; i < 32; ++i) {
      const float vv = vl[i * 68 + d];
      const float* kr = &kp[i * 272 + mg * 68];
#pragma unroll
      for (int jj = 0; jj < 17; ++jj) {
        float4 k4 = *(const float4*)&kr[jj * 4];
        acc[4 * jj + 0] += k4.x * vv;
        acc[4 * jj + 1] += k4.y * vv;
        acc[4 * jj + 2] += k4.z * vv;
        acc[4 * jj + 3] += k4.w * vv;
      }
    }
  }
  const size_t cb = (size_t)bh * MMR * DHD;
#pragma unroll
  for (int jj = 0; jj < 68; ++jj) {
    int m = mg * 68 + jj;
    if (m < MMR) ctxg[cb + (size_t)m * 64 + d] = acc[jj];
  }
  for (int m = tid; m < MMR; m += 256) ksumg[bh * MMR + m] = ks[m];
}

// ---------------- attn = (qp @ ctx)/den  (block = (b,h) x 32 query rows) ----------------
__global__ __launch_bounds__(256) void attn_kernel(
    const float* __restrict__ Qbuf, const float* __restrict__ ctxg,
    const float* __restrict__ ksumg, const float* __restrict__ proj,
    float* __restrict__ attnb)
{
  __shared__ float pj[272 * 68];
  __shared__ float ql[32 * 68];
  __shared__ float qp[32 * 272];
  __shared__ float ks[272];
  __shared__ float den_s[32];
  const int tid = threadIdx.x;
  const int bh = blockIdx.x >> 5;
  const int nc = blockIdx.x & 31;
  const int b = bh >> 3, h = bh & 7;
  const int n0 = nc * 32;
  stage_proj(pj, proj, tid);
  for (int m = tid; m < 272; m += 256) ks[m] = (m < MMR) ? ksumg[bh * MMR + m] : 0.f;
  for (int idx = tid; idx < 2048; idx += 256) {
    int r = idx >> 6, dd = idx & 63;
    ql[r * 68 + dd] = Qbuf[((size_t)(b * NPOS + n0 + r)) * DMODEL + h * DHD + dd] * DNSC;
  }
  __syncthreads();
  const int i8 = tid >> 3, ml = tid & 7, mb = ml * 34;
  float dacc[34];
#pragma unroll
  for (int j = 0; j < 34; ++j) dacc[j] = 0.f;
  float diag = 0.f;
  for (int d0 = 0; d0 < 64; d0 += 4) {
    float4 k4 = *(const float4*)&ql[i8 * 68 + d0];
    diag += k4.x * k4.x + k4.y * k4.y + k4.z * k4.z + k4.w * k4.w;
#pragma unroll
    for (int j = 0; j < 34; ++j) {
      float4 p4 = *(const float4*)&pj[(mb + j) * 68 + d0];
      dacc[j] += k4.x * p4.x + k4.y * p4.y + k4.z * p4.z + k4.w * p4.w;
    }
  }
  diag *= 0.5f;
  float mx = NEG_INF;
#pragma unroll
  for (int j = 0; j < 34; ++j) {
    int m = mb + j;
    mx = fmaxf(mx, (m < MMR) ? dacc[j] : NEG_INF);
  }
#pragma unroll
  for (int off = 1; off < 8; off <<= 1) mx = fmaxf(mx, __shfl_xor(mx, off));
  float dp = 0.f;
#pragma unroll
  for (int j = 0; j < 34; ++j) {
    int m = mb + j;
    if (m < MMR) {
      float v = RSM * (expf(dacc[j] - diag - mx) + 1e-4f);
      qp[i8 * 272 + m] = v;
      dp += v * ks[m];
    }
  }
  if (ml < 6) qp[i8 * 272 + MMR + ml] = 0.f;
#pragma unroll
  for (int off = 1; off < 8; off <<= 1) dp += __shfl_xor(dp, off);
  if (ml == 0) den_s[i8] = dp;
  __syncthreads();
  const int lane = tid & 63, wid = tid >> 6;
  float acc[8];
#pragma unroll
  for (int t = 0; t < 8; ++t) acc[t] = 0.f;
  const float* cb = ctxg + (size_t)bh * MMR * DHD + lane;
  for (int m0 = 0; m0 < 264; m0 += 4) {
    float c0 = cb[(size_t)(m0 + 0) * 64];
    float c1 = cb[(size_t)(m0 + 1) * 64];
    float c2 = cb[(size_t)(m0 + 2) * 64];
    float c3 = cb[(size_t)(m0 + 3) * 64];
#pragma unroll
    for (int t = 0; t < 8; ++t) {
      float4 q4 = *(const float4*)&qp[(wid + 4 * t) * 272 + m0];
      acc[t] += q4.x * c0 + q4.y * c1 + q4.z * c2 + q4.w * c3;
    }
  }
  {
    float c0 = cb[264 * 64], c1 = cb[265 * 64];
#pragma unroll
    for (int t = 0; t < 8; ++t)
      acc[t] += qp[(wid + 4 * t) * 272 + 264] * c0 + qp[(wid + 4 * t) * 272 + 265] * c1;
  }
#pragma unroll
  for (int t = 0; t < 8; ++t) {
    int r = wid + 4 * t;
    size_t o = ((size_t)(b * NPOS + n0 + r)) * DMODEL + h * DHD + lane;
    attnb[o] = acc[t] / den_s[r];
  }
}

// ---------------- LayerNorm (one block per row); optional second output ----------------
__global__ __launch_bounds__(256) void ln_kernel(
    const float* __restrict__ in, const float* __restrict__ g, const float* __restrict__ bb,
    float* __restrict__ out, float* __restrict__ out2)
{
  const int row = blockIdx.x, tid = threadIdx.x;
  float2 x = *(const float2*)&in[(size_t)row * DMODEL + tid * 2];
  float s = x.x + x.y, sq = x.x * x.x + x.y * x.y;
#pragma unroll
  for (int off = 32; off > 0; off >>= 1) {
    s += __shfl_down(s, off);
    sq += __shfl_down(sq, off);
  }
  __shared__ float ps[4], pq[4];
  __shared__ float smu, srv;
  const int wv = tid >> 6, ln = tid & 63;
  if (ln == 0) { ps[wv] = s; pq[wv] = sq; }
  __syncthreads();
  if (tid == 0) {
    float S = ps[0] + ps[1] + ps[2] + ps[3];
    float Q = pq[0] + pq[1] + pq[2] + pq[3];
    float mu = S / 512.f;
    float var = Q / 512.f - mu * mu;
    smu = mu;
    srv = 1.0f / sqrtf(var + 1e-5f);
  }
  __syncthreads();
  const float mu = smu, rv = srv;
  const int c = tid * 2;
  float y0 = (x.x - mu) * rv * g[c] + bb[c];
  float y1 = (x.y - mu) * rv * g[c + 1] + bb[c + 1];
  out[(size_t)row * DMODEL + c] = y0;
  out[(size_t)row * DMODEL + c + 1] = y1;
  if (out2) {
    out2[(size_t)row * DMODEL + c] = y0;
    out2[(size_t)row * DMODEL + c + 1] = y1;
  }
}

// ---------------- gating: logits -> top2 -> softmax -> expert lists ----------------
__global__ __launch_bounds__(64) void zero_cnt_kernel(int* __restrict__ cnt)
{
  if (threadIdx.x < NEXP) cnt[threadIdx.x] = 0;
}

__global__ __launch_bounds__(256) void gate_kernel(
    const float* __restrict__ h1, const float* __restrict__ gw, const float* __restrict__ gb,
    int* __restrict__ cnt, int* __restrict__ toks, float* __restrict__ gws)
{
  const int wv = threadIdx.x >> 6, ln = threadIdx.x & 63;
  const int tok = blockIdx.x * 4 + wv;
  const float* hr = h1 + (size_t)tok * DMODEL;
  float p0 = 0, p1 = 0, p2 = 0, p3 = 0;
#pragma unroll
  for (int k = 0; k < 8; ++k) {
    float xv = hr[ln + 64 * k];
    p0 += xv * gw[0 * DMODEL + ln + 64 * k];
    p1 += xv * gw[1 * DMODEL + ln + 64 * k];
    p2 += xv * gw[2 * DMODEL + ln + 64 * k];
    p3 += xv * gw[3 * DMODEL + ln + 64 * k];
  }
#pragma unroll
  for (int off = 32; off > 0; off >>= 1) {
    p0 += __shfl_down(p0, off);
    p1 += __shfl_down(p1, off);
    p2 += __shfl_down(p2, off);
    p3 += __shfl_down(p3, off);
  }
  if (ln == 0) {
    p0 += gb[0]; p1 += gb[1]; p2 += gb[2]; p3 += gb[3];
    int i0 = 0; float v0 = p0;
    if (p1 > v0) { v0 = p1; i0 = 1; }
    if (p2 > v0) { v0 = p2; i0 = 2; }
    if (p3 > v0) { v0 = p3; i0 = 3; }
    int i1 = -1; float v1 = NEG_INF;
    if (i0 != 0 && p0 > v1) { v1 = p0; i1 = 0; }
    if (i0 != 1 && p1 > v1) { v1 = p1; i1 = 1; }
    if (i0 != 2 && p2 > v1) { v1 = p2; i1 = 2; }
    if (i0 != 3 && p3 > v1) { v1 = p3; i1 = 3; }
    float e = expf(v1 - v0);
    float w0 = 1.f / (1.f + e);
    float w1 = e / (1.f + e);
    int pos0 = atomicAdd(&cnt[i0], 1);
    toks[i0 * NTOK + pos0] = tok;
    gws[i0 * NTOK + pos0] = w0;
    int pos1 = atomicAdd(&cnt[i1], 1);
    toks[i1 * NTOK + pos1] = tok;
    gws[i1 * NTOK + pos1] = w1;
  }
}

// ---------------- weight transpose + fp32->fp16: out[e][c][r] = in[e][r][c] ----------------
__global__ __launch_bounds__(256) void transpose_f16_kernel(
    const float* __restrict__ in, _Float16* __restrict__ outp, int R, int C)
{
  __shared__ float tl[32][33];
  const int bid = blockIdx.x;
  const int e  = bid >> 10;          // 1024 tiles per expert (R*C/1024 == 1M)
  const int t2 = bid & 1023;
  const int tC = C >> 5;
  const int r0 = (t2 / tC) << 5;
  const int c0 = (t2 % tC) << 5;
  const float* ine  = in   + (size_t)e * R * C;
  _Float16*    oute = outp + (size_t)e * R * C;
  const int ci = threadIdx.x & 31, ri = threadIdx.x >> 5;
#pragma unroll
  for (int i = 0; i < 4; ++i)
    tl[ri + i * 8][ci] = ine[(size_t)(r0 + ri + i * 8) * C + c0 + ci];
  __syncthreads();
  const int rr = threadIdx.x & 31, cc = threadIdx.x >> 5;
#pragma unroll
  for (int i = 0; i < 4; ++i)
    oute[(size_t)(c0 + cc + i * 8) * R + r0 + rr] = (_Float16)tl[rr][cc + i * 8];
}

// ---------------- grouped MoE via fp16 MFMA -------------------------------------------
// 64-token tiles, 4 waves; wave w owns rows [16w,16w+16). Per f-chunk (64 wide):
// GEMM1 hmid = t@w1 (MFMA) -> bias+relu -> wave-private LDS bounce -> GEMM2 y += hmid@w2.
// Frag maps (mfma_f32_16x16x32_f16): A row=l&15,k=8*(l>>4)+j; B col=l&15 same k;
// D col=l&15,row=4*(l>>4)+reg.
__global__ __launch_bounds__(256) void moe_mfma_kernel(
    const float* __restrict__ h1, const _Float16* __restrict__ w1t, const float* __restrict__ b1,
    const _Float16* __restrict__ w2t, const float* __restrict__ b2,
    const int* __restrict__ cnt, const int* __restrict__ toks, const float* __restrict__ gws,
    float* __restrict__ Z)
{
  __shared__ _Float16 t_lds[64 * 520];     // 64 tokens x 512, pad 8 (row 1040B, 16B-aligned)
  __shared__ _Float16 hm[4 * 16 * 72];     // per-wave hmid bounce (16 x 64, pad 8)
  __shared__ int   tk_s[64];
  __shared__ float gw_s[64];
  const int tid = threadIdx.x;
  const int e = blockIdx.x >> 10;
  const int tile = blockIdx.x & 1023;
  const int cn = cnt[e];
  if (tile * 64 >= cn) return;
  if (tid < 64) {
    int idx = tile * 64 + tid;
    if (idx < cn) { tk_s[tid] = toks[e * NTOK + idx]; gw_s[tid] = gws[e * NTOK + idx]; }
    else          { tk_s[tid] = -1;                   gw_s[tid] = 0.f; }
  }
  __syncthreads();
  // stage token rows fp32 -> fp16 LDS
  for (int it = tid; it < 64 * 128; it += 256) {
    int r = it >> 7, c4 = (it & 127) * 4;
    int tk = tk_s[r];
    float4 v = make_float4(0.f, 0.f, 0.f, 0.f);
    if (tk >= 0) v = *(const float4*)&h1[(size_t)tk * DMODEL + c4];
    _Float16* p = &t_lds[r * 520 + c4];
    p[0] = (_Float16)v.x; p[1] = (_Float16)v.y; p[2] = (_Float16)v.z; p[3] = (_Float16)v.w;
  }
  __syncthreads();

  const int w = tid >> 6, l = tid & 63;
  const int lr = l & 15, lg = l >> 4;
  _Float16* hmW = &hm[w * 16 * 72];
  const _Float16* w1e = w1t + (size_t)e * NDFF * DMODEL;   // [f][k]
  const _Float16* w2e = w2t + (size_t)e * DMODEL * NDFF;   // [n][f]

  f32x4 acc2[32];
#pragma unroll
  for (int nt = 0; nt < 32; ++nt) acc2[nt] = (f32x4){0.f, 0.f, 0.f, 0.f};

  for (int fc = 0; fc < 32; ++fc) {
    // ---- GEMM1: hmid[16 rows][64 f] over K=512 ----
    f32x4 acc1[4];
#pragma unroll
    for (int ft = 0; ft < 4; ++ft) acc1[ft] = (f32x4){0.f, 0.f, 0.f, 0.f};
    for (int ks = 0; ks < 16; ++ks) {
      half8 a = *(const half8*)&t_lds[(w * 16 + lr) * 520 + ks * 32 + lg * 8];
#pragma unroll
      for (int ft = 0; ft < 4; ++ft) {
        half8 bfr = *(const half8*)&w1e[(size_t)(fc * 64 + ft * 16 + lr) * DMODEL + ks * 32 + lg * 8];
        acc1[ft] = __builtin_amdgcn_mfma_f32_16x16x32_f16(a, bfr, acc1[ft], 0, 0, 0);
      }
    }
    // bias + relu -> fp16 bounce (D-frag -> memory)
#pragma unroll
    for (int ft = 0; ft < 4; ++ft) {
      float b1v = b1[e * NDFF + fc * 64 + ft * 16 + lr];
#pragma unroll
      for (int r = 0; r < 4; ++r) {
        float hv = fmaxf(acc1[ft][r] + b1v, 0.f);
        hmW[(lg * 4 + r) * 72 + ft * 16 + lr] = (_Float16)hv;
      }
    }
    // ---- GEMM2: y[16 rows][512] += hmid @ w2 (K=64 this chunk) ----
#pragma unroll
    for (int ks2 = 0; ks2 < 2; ++ks2) {
      half8 a = *(const half8*)&hmW[lr * 72 + ks2 * 32 + lg * 8];
#pragma unroll
      for (int nt = 0; nt < 32; ++nt) {
        half8 bfr = *(const half8*)&w2e[(size_t)(nt * 16 + lr) * NDFF + fc * 64 + ks2 * 32 + lg * 8];
        acc2[nt] = __builtin_amdgcn_mfma_f32_16x16x32_f16(a, bfr, acc2[nt], 0, 0, 0);
      }
    }
  }

  // epilogue: Z[tok][n] += (y + b2[n]) * gw
  const float* b2e = b2 + e * DMODEL;
#pragma unroll
  for (int nt = 0; nt < 32; ++nt) {
    float b2v = b2e[nt * 16 + lr];
#pragma unroll
    for (int r = 0; r < 4; ++r) {
      int row = w * 16 + lg * 4 + r;
      int tk = tk_s[row];
      if (tk >= 0)
        atomicAdd(&Z[(size_t)tk * DMODEL + nt * 16 + lr], (acc2[nt][r] + b2v) * gw_s[row]);
    }
  }
}

// ---------------- launch ----------------
extern "C" void kernel_launch(void* const* d_in, const int* in_sizes, int n_in,
                              void* d_out, int out_size, void* d_ws, size_t ws_size,
                              hipStream_t stream) {
  const float* x     = (const float*)d_in[0];
  const float* emb_w = (const float*)d_in[1];
  const float* wq    = (const float*)d_in[2];
  const float* bq    = (const float*)d_in[3];
  const float* wk    = (const float*)d_in[4];
  const float* bk    = (const float*)d_in[5];
  const float* wv    = (const float*)d_in[6];
  const float* bv    = (const float*)d_in[7];
  const float* wo    = (const float*)d_in[8];
  const float* bo    = (const float*)d_in[9];
  const float* proj  = (const float*)d_in[10];
  const float* ln2g  = (const float*)d_in[11];
  const float* ln2b  = (const float*)d_in[12];
  const float* ln3g  = (const float*)d_in[13];
  const float* ln3b  = (const float*)d_in[14];
  const float* gatew = (const float*)d_in[15];
  const float* gateb = (const float*)d_in[16];
  const float* w1    = (const float*)d_in[17];
  const float* b1    = (const float*)d_in[18];
  const float* w2    = (const float*)d_in[19];
  const float* b2    = (const float*)d_in[20];
  float* out = (float*)d_out;
  float* ws  = (float*)d_ws;

  if (ws_size < F_END * sizeof(float)) {
    fallback_zero_kernel<<<NTOK * 2, 256, 0, stream>>>(out);
    return;
  }

  float* BUF1 = ws + F_BUF1;   // K -> Q -> pre -> Z
  float* BUF2 = out;           // V -> attn -> h1 (d_out reused as scratch)
  int*   cnt  = (int*)(ws + F_CNTI);
  int*   toks = (int*)(ws + F_TOKI);
  float* gwf  = ws + F_GWF;
  // fp16 transposed weights overlay the CTX region (dead after attn_kernel)
  _Float16* w1t = (_Float16*)(ws + F_CTX);                  // [E][2048][512]
  _Float16* w2t = w1t + (size_t)NEXP * NDFF * DMODEL;       // [E][512][2048]

  zero_cnt_kernel<<<1, 64, 0, stream>>>(cnt);
  effmat_kernel<<<1536, 128, 0, stream>>>(wq, wk, wv, emb_w, ws + F_EFF);
  // K = x @ Keff^T + bk -> BUF1
  gemm_nt_kernel<<<4096, 256, 0, stream>>>(x, ws + F_EFF + 65536, CIN, nullptr, nullptr, 0, bk, BUF1, DMODEL, 8);
  // V = x @ Veff^T + bv -> BUF2 (d_out)
  gemm_nt_kernel<<<4096, 256, 0, stream>>>(x, ws + F_EFF + 131072, CIN, nullptr, nullptr, 0, bv, BUF2, DMODEL, 8);
  kdash_max_kernel<<<2048, 256, 0, stream>>>(BUF1, proj, ws + F_PART);
  reduce_max_kernel<<<1, 256, 0, stream>>>(ws + F_PART, ws + F_STAB, 2048);
  ctx_kernel<<<256, 256, 0, stream>>>(BUF1, BUF2, proj, ws + F_STAB, ws + F_CTX, ws + F_KSUM);
  // Q = x @ Qeff^T + bq -> BUF1 (K dead)
  gemm_nt_kernel<<<4096, 256, 0, stream>>>(x, ws + F_EFF, CIN, nullptr, nullptr, 0, bq, BUF1, DMODEL, 8);
  attn_kernel<<<8192, 256, 0, stream>>>(BUF1, ws + F_CTX, ws + F_KSUM, proj, BUF2);
  // ctx now dead: build fp16 transposed weights in its place
  transpose_f16_kernel<<<4096, 256, 0, stream>>>(w1, w1t, DMODEL, NDFF);   // w1t[e][f][k]
  transpose_f16_kernel<<<4096, 256, 0, stream>>>(w2, w2t, NDFF, DMODEL);   // w2t[e][n][f]
  // pre = attn@wo^T + x@emb_w^T + bo -> BUF1
  gemm_nt_kernel<<<4096, 256, 0, stream>>>(BUF2, wo, DMODEL, x, emb_w, CIN, bo, BUF1, DMODEL, 8);
  // h1 = LN(pre) -> BUF2; Z = h1 -> BUF1
  ln_kernel<<<NTOK, 256, 0, stream>>>(BUF1, ln2g, ln2b, BUF2, BUF1);
  gate_kernel<<<8192, 256, 0, stream>>>(BUF2, gatew, gateb, cnt, toks, gwf);
  // grouped sparse MoE via MFMA, scatter-add into Z (BUF1)
  moe_mfma_kernel<<<4096, 256, 0, stream>>>(BUF2, w1t, b1, w2t, b2, cnt, toks, gwf, BUF1);
  ln_kernel<<<NTOK, 256, 0, stream>>>(BUF1, ln3g, ln3b, out, nullptr);
}

// Round 4
// 4495.009 us; speedup vs baseline: 2.8318x; 1.5725x over previous
//
#include <hip/hip_runtime.h>
#include <math.h>

// Problem dims
#define NBATCH 32
#define NPOS   1024
#define NTOK   32768          // NBATCH*NPOS
#define DMODEL 512
#define NHEAD  8
#define DHD    64
#define NROWS  262144         // NTOK*NHEAD
#define MMR    266            // random-feature count
#define NDFF   2048
#define NEXP   4
#define CIN    128            // PL*CIN = flattened patch dim

#define DNSC   0.35355339059327373f   // 64^-0.25
#define RSM    0.06131393394849658f   // 266^-0.5
#define NEG_INF -3.0e38f

typedef _Float16 half8 __attribute__((ext_vector_type(8)));
typedef float    f32x4 __attribute__((ext_vector_type(4)));

// ---------------- workspace layout (float offsets), total 21,664,288 floats = 86.7 MB ----
static const size_t F_BUF1 = 0;          // 16777216 (K -> Q -> pre -> Z)
static const size_t F_CTX  = 16777216;   // 4358144 (256*266*64); reused for fp16 weights after attn
static const size_t F_KSUM = 21135360;   // 68096 (256*266)
static const size_t F_PART = 21203456;   // 2048
static const size_t F_STAB = 21205504;   // 16
static const size_t F_EFF  = 21205520;   // 3*512*128 = 196608
static const size_t F_CNTI = 21402128;   // 16 (ints)
static const size_t F_TOKI = 21402144;   // 4*32768 ints
static const size_t F_GWF  = 21533216;   // 4*32768 floats
static const size_t F_END  = 21664288;

// ---------------- fallback (ws too small): write zeros, fail cleanly, no fault -----------
__global__ __launch_bounds__(256) void fallback_zero_kernel(float* __restrict__ out) {
  out[(size_t)blockIdx.x * 256 + threadIdx.x] = 0.f;
}

__global__ __launch_bounds__(256) void zero_range_kernel(float* __restrict__ p, int n) {
  int i = blockIdx.x * 256 + threadIdx.x;
  if (i < n) p[i] = 0.f;
}

// ---------------- effective QKV matrices: eff[mat] = W[mat] @ emb_w  (512x128) ----------
__global__ __launch_bounds__(128) void effmat_kernel(
    const float* __restrict__ wq, const float* __restrict__ wk, const float* __restrict__ wv,
    const float* __restrict__ emb, float* __restrict__ eff)
{
  __shared__ float wrow[512];
  const int bid = blockIdx.x;          // 0..1535
  const int mat = bid >> 9;
  const int n   = bid & 511;
  const float* W = (mat == 0) ? wq : ((mat == 1) ? wk : wv);
  const int tid = threadIdx.x;         // 128
  for (int i = tid; i < 512; i += 128) wrow[i] = W[n * 512 + i];
  __syncthreads();
  float acc = 0.f;
  for (int d = 0; d < 512; ++d) acc += wrow[d] * emb[d * CIN + tid];
  eff[mat * 65536 + n * CIN + tid] = acc;
}

// ---------------- helpers ----------------
__device__ __forceinline__ void stage_proj(float* pj, const float* __restrict__ proj, int tid) {
  for (int idx = tid; idx < 272 * 68; idx += 256) pj[idx] = 0.f;
  __syncthreads();
  for (int idx = tid; idx < MMR * 64; idx += 256) {
    int m = idx >> 6, d = idx & 63;
    pj[m * 68 + d] = proj[idx];
  }
}

// ------- generic GEMM: C = A(MxK)*W(NxK)^T [+ A2(MxK2)*W2(NxK2)^T] + bias --------------
__global__ __launch_bounds__(256) void gemm_nt_kernel(
    const float* __restrict__ A, const float* __restrict__ W, int K,
    const float* __restrict__ A2, const float* __restrict__ W2, int K2,
    const float* __restrict__ bias, float* __restrict__ C, int N, int ncb)
{
  __shared__ float As[32][64];
  __shared__ float Ws[32][64];
  const int tid  = threadIdx.x;
  const int bx   = blockIdx.x % ncb;
  const int by   = blockIdx.x / ncb;
  const int row0 = by * 64, col0 = bx * 64;
  const int tx   = tid & 15, ty = tid >> 4;
  const int lr   = tid >> 3;
  const int lk   = (tid & 7) * 4;
  float acc[4][4] = {};
  for (int pass = 0; pass < 2; ++pass) {
    const float* Ap = pass ? A2 : A;
    const float* Wp = pass ? W2 : W;
    const int    Kp = pass ? K2 : K;
    if (!Ap) continue;
    for (int k0 = 0; k0 < Kp; k0 += 32) {
      __syncthreads();
#pragma unroll
      for (int rr = 0; rr < 2; ++rr) {
        const int r = lr + rr * 32;
        float4 a4 = *(const float4*)&Ap[(size_t)(row0 + r) * Kp + k0 + lk];
        As[lk + 0][r] = a4.x; As[lk + 1][r] = a4.y; As[lk + 2][r] = a4.z; As[lk + 3][r] = a4.w;
        float4 w4 = *(const float4*)&Wp[(size_t)(col0 + r) * Kp + k0 + lk];
        Ws[lk + 0][r] = w4.x; Ws[lk + 1][r] = w4.y; Ws[lk + 2][r] = w4.z; Ws[lk + 3][r] = w4.w;
      }
      __syncthreads();
#pragma unroll
      for (int kk = 0; kk < 32; ++kk) {
        float4 av = *(const float4*)&As[kk][ty * 4];
        float4 wv = *(const float4*)&Ws[kk][tx * 4];
        acc[0][0] += av.x * wv.x; acc[0][1] += av.x * wv.y; acc[0][2] += av.x * wv.z; acc[0][3] += av.x * wv.w;
        acc[1][0] += av.y * wv.x; acc[1][1] += av.y * wv.y; acc[1][2] += av.y * wv.z; acc[1][3] += av.y * wv.w;
        acc[2][0] += av.z * wv.x; acc[2][1] += av.z * wv.y; acc[2][2] += av.z * wv.z; acc[2][3] += av.z * wv.w;
        acc[3][0] += av.w * wv.x; acc[3][1] += av.w * wv.y; acc[3][2] += av.w * wv.z; acc[3][3] += av.w * wv.w;
      }
    }
  }
#pragma unroll
  for (int i = 0; i < 4; ++i) {
    const int row = row0 + ty * 4 + i;
    const int col = col0 + tx * 4;
    float4 o = make_float4(acc[i][0], acc[i][1], acc[i][2], acc[i][3]);
    if (bias) {
      float4 b4 = *(const float4*)&bias[col];
      o.x += b4.x; o.y += b4.y; o.z += b4.z; o.w += b4.w;
    }
    *(float4*)&C[(size_t)row * N + col] = o;
  }
}

// ---------------- global max of k-dash (for key stabilizer) ----------------
__global__ __launch_bounds__(256) void kdash_max_kernel(
    const float* __restrict__ Kbuf, const float* __restrict__ proj, float* __restrict__ partial)
{
  __shared__ float pj[272 * 68];
  __shared__ float kl[32 * 68];
  __shared__ float red[256];
  const int tid = threadIdx.x;
  stage_proj(pj, proj, tid);
  const int i8 = tid >> 3, ml = tid & 7, mb = ml * 34;
  const size_t rid0 = (size_t)blockIdx.x * 128;
  float mx = NEG_INF;
  for (int ch = 0; ch < 4; ++ch) {
    __syncthreads();
    for (int idx = tid; idx < 2048; idx += 256) {
      int r = idx >> 6, dd = idx & 63;
      kl[r * 68 + dd] = Kbuf[(rid0 + ch * 32 + r) * 64 + dd] * DNSC;
    }
    __syncthreads();
    float dacc[34];
#pragma unroll
    for (int j = 0; j < 34; ++j) dacc[j] = 0.f;
    for (int d0 = 0; d0 < 64; d0 += 4) {
      float4 k4 = *(const float4*)&kl[i8 * 68 + d0];
#pragma unroll
      for (int j = 0; j < 34; ++j) {
        float4 p4 = *(const float4*)&pj[(mb + j) * 68 + d0];
        dacc[j] += k4.x * p4.x + k4.y * p4.y + k4.z * p4.z + k4.w * p4.w;
      }
    }
#pragma unroll
    for (int j = 0; j < 34; ++j) {
      int m = mb + j;
      mx = fmaxf(mx, (m < MMR) ? dacc[j] : NEG_INF);
    }
  }
  red[tid] = mx;
  __syncthreads();
  for (int st = 128; st > 0; st >>= 1) {
    if (tid < st) red[tid] = fmaxf(red[tid], red[tid + st]);
    __syncthreads();
  }
  if (tid == 0) partial[blockIdx.x] = red[0];
}

__global__ __launch_bounds__(256) void reduce_max_kernel(
    const float* __restrict__ part, float* __restrict__ stab, int n)
{
  __shared__ float red[256];
  float m = NEG_INF;
  for (int i = threadIdx.x; i < n; i += 256) m = fmaxf(m, part[i]);
  red[threadIdx.x] = m;
  __syncthreads();
  for (int st = 128; st > 0; st >>= 1) {
    if (threadIdx.x < st) red[threadIdx.x] = fmaxf(red[threadIdx.x], red[threadIdx.x + st]);
    __syncthreads();
  }
  if (threadIdx.x == 0) stab[0] = red[0];
}

// ---------------- ctx += kp^T @ v, ksum += sum_n kp  (block = (b,h) x 256-pos chunk) ----
__global__ __launch_bounds__(256) void ctx_kernel(
    const float* __restrict__ Kbuf, const float* __restrict__ Vbuf,
    const float* __restrict__ proj, const float* __restrict__ stabp,
    float* __restrict__ ctxg, float* __restrict__ ksumg)
{
  __shared__ float pj[272 * 68];
  __shared__ float kl[32 * 68];
  __shared__ float vl[32 * 68];
  __shared__ float kp[32 * 272];
  __shared__ float ks[272];
  const int tid = threadIdx.x;
  const int bh = blockIdx.x & 255;
  const int chunk = blockIdx.x >> 8;
  const int b = bh >> 3, h = bh & 7;
  const float stab = stabp[0];
  stage_proj(pj, proj, tid);
  for (int m = tid; m < 272; m += 256) ks[m] = 0.f;
  const int d = tid & 63, mg = tid >> 6;
  const int i8 = tid >> 3, ml = tid & 7, mb = ml * 34;
  float acc[68];
#pragma unroll
  for (int jj = 0; jj < 68; ++jj) acc[jj] = 0.f;
  for (int n0 = chunk * 256; n0 < chunk * 256 + 256; n0 += 32) {
    __syncthreads();
    for (int idx = tid; idx < 2048; idx += 256) {
      int r = idx >> 6, dd = idx & 63;
      size_t g = ((size_t)(b * NPOS + n0 + r)) * DMODEL + h * DHD + dd;
      kl[r * 68 + dd] = Kbuf[g] * DNSC;
      vl[r * 68 + dd] = Vbuf[g];
    }
    __syncthreads();
    float dacc[34];
#pragma unroll
    for (int j = 0; j < 34; ++j) dacc[j] = 0.f;
    float diag = 0.f;
    for (int d0 = 0; d0 < 64; d0 += 4) {
      float4 k4 = *(const float4*)&kl[i8 * 68 + d0];
      diag += k4.x * k4.x + k4.y * k4.y + k4.z * k4.z + k4.w * k4.w;
#pragma unroll
      for (int j = 0; j < 34; ++j) {
        float4 p4 = *(const float4*)&pj[(mb + j) * 68 + d0];
        dacc[j] += k4.x * p4.x + k4.y * p4.y + k4.z * p4.z + k4.w * p4.w;
      }
    }
    diag *= 0.5f;
#pragma unroll
    for (int j = 0; j < 34; ++j) {
      int m = mb + j;
      if (m < MMR) kp[i8 * 272 + m] = RSM * (expf(dacc[j] - diag - stab) + 1e-4f);
    }
    if (ml < 6) kp[i8 * 272 + MMR + ml] = 0.f;
    __syncthreads();
    for (int m = tid; m < MMR; m += 256) {
      float s = 0.f;
#pragma unroll 8
      for (int i = 0; i < 32; ++i) s += kp[i * 272 + m];
      ks[m] += s;
    }
    for (int i = 0; i < 32; ++i) {
      const float vv = vl[i * 68 + d];
      const float* kr = &kp[i * 272 + mg * 68];
#pragma unroll
      for (int jj = 0; jj < 17; ++jj) {
        float4 k4 = *(const float4*)&kr[jj * 4];
        acc[4 * jj + 0] += k4.x * vv;
        acc[4 * jj + 1] += k4.y * vv;
        acc[4 * jj + 2] += k4.z * vv;
        acc[4 * jj + 3] += k4.w * vv;
      }
    }
  }
  const size_t cb = (size_t)bh * MMR * DHD;
#pragma unroll
  for (int jj = 0; jj < 68; ++jj) {
    int m = mg * 68 + jj;
    if (m < MMR) atomicAdd(&ctxg[cb + (size_t)m * 64 + d], acc[jj]);
  }
  for (int m = tid; m < MMR; m += 256) atomicAdd(&ksumg[bh * MMR + m], ks[m]);
}

// ---------------- attn = (qp @ ctx)/den  (block = (b,h) x 32 query rows) ----------------
__global__ __launch_bounds__(256) void attn_kernel(
    const float* __restrict__ Qbuf, const float* __restrict__ ctxg,
    const float* __restrict__ ksumg, const float* __restrict__ proj,
    float* __restrict__ attnb)
{
  __shared__ float pj[272 * 68];
  __shared__ float ql[32 * 68];
  __shared__ float qp[32 * 272];
  __shared__ float ks[272];
  __shared__ float den_s[32];
  const int tid = threadIdx.x;
  const int bh = blockIdx.x >> 5;
  const int nc = blockIdx.x & 31;
  const int b = bh >> 3, h = bh & 7;
  const int n0 = nc * 32;
  stage_proj(pj, proj, tid);
  for (int m = tid; m < 272; m += 256) ks[m] = (m < MMR) ? ksumg[bh * MMR + m] : 0.f;
  for (int idx = tid; idx < 2048; idx += 256) {
    int r = idx >> 6, dd = idx & 63;
    ql[r * 68 + dd] = Qbuf[((size_t)(b * NPOS + n0 + r)) * DMODEL + h * DHD + dd] * DNSC;
  }
  __syncthreads();
  const int i8 = tid >> 3, ml = tid & 7, mb = ml * 34;
  float dacc[34];
#pragma unroll
  for (int j = 0; j < 34; ++j) dacc[j] = 0.f;
  float diag = 0.f;
  for (int d0 = 0; d0 < 64; d0 += 4) {
    float4 k4 = *(const float4*)&ql[i8 * 68 + d0];
    diag += k4.x * k4.x + k4.y * k4.y + k4.z * k4.z + k4.w * k4.w;
#pragma unroll
    for (int j = 0; j < 34; ++j) {
      float4 p4 = *(const float4*)&pj[(mb + j) * 68 + d0];
      dacc[j] += k4.x * p4.x + k4.y * p4.y + k4.z * p4.z + k4.w * p4.w;
    }
  }
  diag *= 0.5f;
  float mx = NEG_INF;
#pragma unroll
  for (int j = 0; j < 34; ++j) {
    int m = mb + j;
    mx = fmaxf(mx, (m < MMR) ? dacc[j] : NEG_INF);
  }
#pragma unroll
  for (int off = 1; off < 8; off <<= 1) mx = fmaxf(mx, __shfl_xor(mx, off));
  float dp = 0.f;
#pragma unroll
  for (int j = 0; j < 34; ++j) {
    int m = mb + j;
    if (m < MMR) {
      float v = RSM * (expf(dacc[j] - diag - mx) + 1e-4f);
      qp[i8 * 272 + m] = v;
      dp += v * ks[m];
    }
  }
  if (ml < 6) qp[i8 * 272 + MMR + ml] = 0.f;
#pragma unroll
  for (int off = 1; off < 8; off <<= 1) dp += __shfl_xor(dp, off);
  if (ml == 0) den_s[i8] = dp;
  __syncthreads();
  const int lane = tid & 63, wid = tid >> 6;
  float acc[8];
#pragma unroll
  for (int t = 0; t < 8; ++t) acc[t] = 0.f;
  const float* cb = ctxg + (size_t)bh * MMR * DHD + lane;
  for (int m0 = 0; m0 < 264; m0 += 4) {
    float c0 = cb[(size_t)(m0 + 0) * 64];
    float c1 = cb[(size_t)(m0 + 1) * 64];
    float c2 = cb[(size_t)(m0 + 2) * 64];
    float c3 = cb[(size_t)(m0 + 3) * 64];
#pragma unroll
    for (int t = 0; t < 8; ++t) {
      float4 q4 = *(const float4*)&qp[(wid + 4 * t) * 272 + m0];
      acc[t] += q4.x * c0 + q4.y * c1 + q4.z * c2 + q4.w * c3;
    }
  }
  {
    float c0 = cb[264 * 64], c1 = cb[265 * 64];
#pragma unroll
    for (int t = 0; t < 8; ++t)
      acc[t] += qp[(wid + 4 * t) * 272 + 264] * c0 + qp[(wid + 4 * t) * 272 + 265] * c1;
  }
#pragma unroll
  for (int t = 0; t < 8; ++t) {
    int r = wid + 4 * t;
    size_t o = ((size_t)(b * NPOS + n0 + r)) * DMODEL + h * DHD + lane;
    attnb[o] = acc[t] / den_s[r];
  }
}

// ---------------- LayerNorm (one block per row); optional second output ----------------
__global__ __launch_bounds__(256) void ln_kernel(
    const float* __restrict__ in, const float* __restrict__ g, const float* __restrict__ bb,
    float* __restrict__ out, float* __restrict__ out2)
{
  const int row = blockIdx.x, tid = threadIdx.x;
  float2 x = *(const float2*)&in[(size_t)row * DMODEL + tid * 2];
  float s = x.x + x.y, sq = x.x * x.x + x.y * x.y;
#pragma unroll
  for (int off = 32; off > 0; off >>= 1) {
    s += __shfl_down(s, off);
    sq += __shfl_down(sq, off);
  }
  __shared__ float ps[4], pq[4];
  __shared__ float smu, srv;
  const int wv = tid >> 6, ln = tid & 63;
  if (ln == 0) { ps[wv] = s; pq[wv] = sq; }
  __syncthreads();
  if (tid == 0) {
    float S = ps[0] + ps[1] + ps[2] + ps[3];
    float Q = pq[0] + pq[1] + pq[2] + pq[3];
    float mu = S / 512.f;
    float var = Q / 512.f - mu * mu;
    smu = mu;
    srv = 1.0f / sqrtf(var + 1e-5f);
  }
  __syncthreads();
  const float mu = smu, rv = srv;
  const int c = tid * 2;
  float y0 = (x.x - mu) * rv * g[c] + bb[c];
  float y1 = (x.y - mu) * rv * g[c + 1] + bb[c + 1];
  out[(size_t)row * DMODEL + c] = y0;
  out[(size_t)row * DMODEL + c + 1] = y1;
  if (out2) {
    out2[(size_t)row * DMODEL + c] = y0;
    out2[(size_t)row * DMODEL + c + 1] = y1;
  }
}

// ---------------- gating: logits -> top2 -> softmax -> expert lists ----------------
__global__ __launch_bounds__(64) void zero_cnt_kernel(int* __restrict__ cnt)
{
  if (threadIdx.x < NEXP) cnt[threadIdx.x] = 0;
}

__global__ __launch_bounds__(256) void gate_kernel(
    const float* __restrict__ h1, const float* __restrict__ gw, const float* __restrict__ gb,
    int* __restrict__ cnt, int* __restrict__ toks, float* __restrict__ gws)
{
  const int wv = threadIdx.x >> 6, ln = threadIdx.x & 63;
  const int tok = blockIdx.x * 4 + wv;
  const float* hr = h1 + (size_t)tok * DMODEL;
  float p0 = 0, p1 = 0, p2 = 0, p3 = 0;
#pragma unroll
  for (int k = 0; k < 8; ++k) {
    float xv = hr[ln + 64 * k];
    p0 += xv * gw[0 * DMODEL + ln + 64 * k];
    p1 += xv * gw[1 * DMODEL + ln + 64 * k];
    p2 += xv * gw[2 * DMODEL + ln + 64 * k];
    p3 += xv * gw[3 * DMODEL + ln + 64 * k];
  }
#pragma unroll
  for (int off = 32; off > 0; off >>= 1) {
    p0 += __shfl_down(p0, off);
    p1 += __shfl_down(p1, off);
    p2 += __shfl_down(p2, off);
    p3 += __shfl_down(p3, off);
  }
  if (ln == 0) {
    p0 += gb[0]; p1 += gb[1]; p2 += gb[2]; p3 += gb[3];
    int i0 = 0; float v0 = p0;
    if (p1 > v0) { v0 = p1; i0 = 1; }
    if (p2 > v0) { v0 = p2; i0 = 2; }
    if (p3 > v0) { v0 = p3; i0 = 3; }
    int i1 = -1; float v1 = NEG_INF;
    if (i0 != 0 && p0 > v1) { v1 = p0; i1 = 0; }
    if (i0 != 1 && p1 > v1) { v1 = p1; i1 = 1; }
    if (i0 != 2 && p2 > v1) { v1 = p2; i1 = 2; }
    if (i0 != 3 && p3 > v1) { v1 = p3; i1 = 3; }
    float e = expf(v1 - v0);
    float w0 = 1.f / (1.f + e);
    float w1 = e / (1.f + e);
    int pos0 = atomicAdd(&cnt[i0], 1);
    toks[i0 * NTOK + pos0] = tok;
    gws[i0 * NTOK + pos0] = w0;
    int pos1 = atomicAdd(&cnt[i1], 1);
    toks[i1 * NTOK + pos1] = tok;
    gws[i1 * NTOK + pos1] = w1;
  }
}

// ---------------- weight transpose + fp32->fp16: out[e][c][r] = in[e][r][c] ----------------
__global__ __launch_bounds__(256) void transpose_f16_kernel(
    const float* __restrict__ in, _Float16* __restrict__ outp, int R, int C)
{
  __shared__ float tl[32][33];
  const int bid = blockIdx.x;
  const int e  = bid >> 10;          // 1024 tiles per expert (R*C/1024 == 1M)
  const int t2 = bid & 1023;
  const int tC = C >> 5;
  const int r0 = (t2 / tC) << 5;
  const int c0 = (t2 % tC) << 5;
  const float* ine  = in   + (size_t)e * R * C;
  _Float16*    oute = outp + (size_t)e * R * C;
  const int ci = threadIdx.x & 31, ri = threadIdx.x >> 5;
#pragma unroll
  for (int i = 0; i < 4; ++i)
    tl[ri + i * 8][ci] = ine[(size_t)(r0 + ri + i * 8) * C + c0 + ci];
  __syncthreads();
  const int rr = threadIdx.x & 31, cc = threadIdx.x >> 5;
#pragma unroll
  for (int i = 0; i < 4; ++i)
    oute[(size_t)(c0 + cc + i * 8) * R + r0 + rr] = (_Float16)tl[rr][cc + i * 8];
}

// ---------------- grouped MoE via fp16 MFMA, square-blocked ----------------------------
// 512 threads = 8 waves, 64-token tile, 1 block/CU (LDS ~98.5 KB).
// fc loop: 8 chunks of 256 f. GEMM1: wave owns 64tok x 32f (per ks: 4 A-ds + 2 B-gl -> 8 MFMA).
// hm bounce [64][264] fp16. GEMM2: wave owns 64tok x 64n (per ks2: 4 A-ds + 4 B-gl -> 16 MFMA).
// w1/w2 each read exactly once per block (waves own disjoint f/n ranges).
__global__ __launch_bounds__(512) void moe_mfma_kernel(
    const float* __restrict__ h1, const _Float16* __restrict__ w1t, const float* __restrict__ b1,
    const _Float16* __restrict__ w2t, const float* __restrict__ b2,
    const int* __restrict__ cnt, const int* __restrict__ toks, const float* __restrict__ gws,
    float* __restrict__ Z)
{
  __shared__ _Float16 t_lds[64 * 520];     // 66.6 KB
  __shared__ _Float16 hm[64 * 264];        // 33.8 KB
  __shared__ int   tk_s[64];
  __shared__ float gw_s[64];
  const int tid = threadIdx.x;
  const int e = blockIdx.x >> 10;
  const int tile = blockIdx.x & 1023;
  const int cn = cnt[e];
  if (tile * 64 >= cn) return;
  if (tid < 64) {
    int idx = tile * 64 + tid;
    if (idx < cn) { tk_s[tid] = toks[e * NTOK + idx]; gw_s[tid] = gws[e * NTOK + idx]; }
    else          { tk_s[tid] = -1;                   gw_s[tid] = 0.f; }
  }
  __syncthreads();
  // stage token rows fp32 -> fp16 LDS
  for (int it = tid; it < 64 * 128; it += 512) {
    int r = it >> 7, c4 = (it & 127) * 4;
    int tk = tk_s[r];
    float4 v = make_float4(0.f, 0.f, 0.f, 0.f);
    if (tk >= 0) v = *(const float4*)&h1[(size_t)tk * DMODEL + c4];
    _Float16* p = &t_lds[r * 520 + c4];
    p[0] = (_Float16)v.x; p[1] = (_Float16)v.y; p[2] = (_Float16)v.z; p[3] = (_Float16)v.w;
  }
  __syncthreads();

  const int w = tid >> 6, l = tid & 63;
  const int lr = l & 15, lg = l >> 4;
  const _Float16* w1e = w1t + (size_t)e * NDFF * DMODEL;   // [f][k]
  const _Float16* w2e = w2t + (size_t)e * DMODEL * NDFF;   // [n][f]
  const float* b1e = b1 + e * NDFF;

  f32x4 acc2[4][4];
#pragma unroll
  for (int mt = 0; mt < 4; ++mt)
#pragma unroll
    for (int nt = 0; nt < 4; ++nt) acc2[mt][nt] = (f32x4){0.f, 0.f, 0.f, 0.f};

  for (int fc = 0; fc < 8; ++fc) {
    // ---- GEMM1: hmid[64 tok][f = fc*256 + w*32 + nt1*16 + lr] over K=512 ----
    f32x4 acc1[4][2];
#pragma unroll
    for (int mt = 0; mt < 4; ++mt)
#pragma unroll
      for (int nt1 = 0; nt1 < 2; ++nt1) acc1[mt][nt1] = (f32x4){0.f, 0.f, 0.f, 0.f};
#pragma unroll
    for (int ks = 0; ks < 16; ++ks) {
      half8 am[4];
#pragma unroll
      for (int mt = 0; mt < 4; ++mt)
        am[mt] = *(const half8*)&t_lds[(mt * 16 + lr) * 520 + ks * 32 + lg * 8];
#pragma unroll
      for (int nt1 = 0; nt1 < 2; ++nt1) {
        half8 bfr = *(const half8*)&w1e[(size_t)(fc * 256 + w * 32 + nt1 * 16 + lr) * DMODEL + ks * 32 + lg * 8];
#pragma unroll
        for (int mt = 0; mt < 4; ++mt)
          acc1[mt][nt1] = __builtin_amdgcn_mfma_f32_16x16x32_f16(am[mt], bfr, acc1[mt][nt1], 0, 0, 0);
      }
    }
    // bias + relu -> hm (D-frag: row = mt*16 + lg*4 + r (token), col = w*32 + nt1*16 + lr)
#pragma unroll
    for (int nt1 = 0; nt1 < 2; ++nt1) {
      float b1v = b1e[fc * 256 + w * 32 + nt1 * 16 + lr];
#pragma unroll
      for (int mt = 0; mt < 4; ++mt)
#pragma unroll
        for (int r = 0; r < 4; ++r)
          hm[(mt * 16 + lg * 4 + r) * 264 + w * 32 + nt1 * 16 + lr] =
              (_Float16)fmaxf(acc1[mt][nt1][r] + b1v, 0.f);
    }
    __syncthreads();
    // ---- GEMM2: y[64 tok][n = w*64 + nt*16 + lr] += hm @ w2 (K-chunk 256) ----
#pragma unroll
    for (int ks2 = 0; ks2 < 8; ++ks2) {
      half8 am[4];
#pragma unroll
      for (int mt = 0; mt < 4; ++mt)
        am[mt] = *(const half8*)&hm[(mt * 16 + lr) * 264 + ks2 * 32 + lg * 8];
#pragma unroll
      for (int nt = 0; nt < 4; ++nt) {
        half8 bfr = *(const half8*)&w2e[(size_t)(w * 64 + nt * 16 + lr) * NDFF + fc * 256 + ks2 * 32 + lg * 8];
#pragma unroll
        for (int mt = 0; mt < 4; ++mt)
          acc2[mt][nt] = __builtin_amdgcn_mfma_f32_16x16x32_f16(am[mt], bfr, acc2[mt][nt], 0, 0, 0);
      }
    }
    __syncthreads();   // hm reused next fc
  }

  // epilogue: Z[tok][n] += (y + b2[n]) * gw ; col = w*64 + nt*16 + lr, row = mt*16+lg*4+r
  const float* b2e = b2 + e * DMODEL;
#pragma unroll
  for (int nt = 0; nt < 4; ++nt) {
    float b2v = b2e[w * 64 + nt * 16 + lr];
#pragma unroll
    for (int mt = 0; mt < 4; ++mt) {
#pragma unroll
      for (int r = 0; r < 4; ++r) {
        int row = mt * 16 + lg * 4 + r;
        int tk = tk_s[row];
        if (tk >= 0)
          atomicAdd(&Z[(size_t)tk * DMODEL + w * 64 + nt * 16 + lr],
                    (acc2[mt][nt][r] + b2v) * gw_s[row]);
      }
    }
  }
}

// ---------------- launch ----------------
extern "C" void kernel_launch(void* const* d_in, const int* in_sizes, int n_in,
                              void* d_out, int out_size, void* d_ws, size_t ws_size,
                              hipStream_t stream) {
  const float* x     = (const float*)d_in[0];
  const float* emb_w = (const float*)d_in[1];
  const float* wq    = (const float*)d_in[2];
  const float* bq    = (const float*)d_in[3];
  const float* wk    = (const float*)d_in[4];
  const float* bk    = (const float*)d_in[5];
  const float* wv    = (const float*)d_in[6];
  const float* bv    = (const float*)d_in[7];
  const float* wo    = (const float*)d_in[8];
  const float* bo    = (const float*)d_in[9];
  const float* proj  = (const float*)d_in[10];
  const float* ln2g  = (const float*)d_in[11];
  const float* ln2b  = (const float*)d_in[12];
  const float* ln3g  = (const float*)d_in[13];
  const float* ln3b  = (const float*)d_in[14];
  const float* gatew = (const float*)d_in[15];
  const float* gateb = (const float*)d_in[16];
  const float* w1    = (const float*)d_in[17];
  const float* b1    = (const float*)d_in[18];
  const float* w2    = (const float*)d_in[19];
  const float* b2    = (const float*)d_in[20];
  float* out = (float*)d_out;
  float* ws  = (float*)d_ws;

  if (ws_size < F_END * sizeof(float)) {
    fallback_zero_kernel<<<NTOK * 2, 256, 0, stream>>>(out);
    return;
  }

  float* BUF1 = ws + F_BUF1;   // K -> Q -> pre -> Z
  float* BUF2 = out;           // V -> attn -> h1 (d_out reused as scratch)
  int*   cnt  = (int*)(ws + F_CNTI);
  int*   toks = (int*)(ws + F_TOKI);
  float* gwf  = ws + F_GWF;
  // fp16 transposed weights overlay the CTX region (dead after attn_kernel)
  _Float16* w1t = (_Float16*)(ws + F_CTX);                  // [E][2048][512]
  _Float16* w2t = w1t + (size_t)NEXP * NDFF * DMODEL;       // [E][512][2048]

  zero_cnt_kernel<<<1, 64, 0, stream>>>(cnt);
  // zero ctx + ksum (now atomically accumulated)
  zero_range_kernel<<<17292, 256, 0, stream>>>(ws + F_CTX, 4358144 + 68096);
  effmat_kernel<<<1536, 128, 0, stream>>>(wq, wk, wv, emb_w, ws + F_EFF);
  // K = x @ Keff^T + bk -> BUF1
  gemm_nt_kernel<<<4096, 256, 0, stream>>>(x, ws + F_EFF + 65536, CIN, nullptr, nullptr, 0, bk, BUF1, DMODEL, 8);
  // V = x @ Veff^T + bv -> BUF2 (d_out)
  gemm_nt_kernel<<<4096, 256, 0, stream>>>(x, ws + F_EFF + 131072, CIN, nullptr, nullptr, 0, bv, BUF2, DMODEL, 8);
  kdash_max_kernel<<<2048, 256, 0, stream>>>(BUF1, proj, ws + F_PART);
  reduce_max_kernel<<<1, 256, 0, stream>>>(ws + F_PART, ws + F_STAB, 2048);
  // ctx & ksum per (b,h), 4 position-chunks per head
  ctx_kernel<<<1024, 256, 0, stream>>>(BUF1, BUF2, proj, ws + F_STAB, ws + F_CTX, ws + F_KSUM);
  // Q = x @ Qeff^T + bq -> BUF1 (K dead)
  gemm_nt_kernel<<<4096, 256, 0, stream>>>(x, ws + F_EFF, CIN, nullptr, nullptr, 0, bq, BUF1, DMODEL, 8);
  attn_kernel<<<8192, 256, 0, stream>>>(BUF1, ws + F_CTX, ws + F_KSUM, proj, BUF2);
  // ctx now dead: build fp16 transposed weights in its place
  transpose_f16_kernel<<<4096, 256, 0, stream>>>(w1, w1t, DMODEL, NDFF);   // w1t[e][f][k]
  transpose_f16_kernel<<<4096, 256, 0, stream>>>(w2, w2t, NDFF, DMODEL);   // w2t[e][n][f]
  // pre = attn@wo^T + x@emb_w^T + bo -> BUF1
  gemm_nt_kernel<<<4096, 256, 0, stream>>>(BUF2, wo, DMODEL, x, emb_w, CIN, bo, BUF1, DMODEL, 8);
  // h1 = LN(pre) -> BUF2; Z = h1 -> BUF1
  ln_kernel<<<NTOK, 256, 0, stream>>>(BUF1, ln2g, ln2b, BUF2, BUF1);
  gate_kernel<<<8192, 256, 0, stream>>>(BUF2, gatew, gateb, cnt, toks, gwf);
  // grouped sparse MoE via MFMA, scatter-add into Z (BUF1)
  moe_mfma_kernel<<<4096, 512, 0, stream>>>(BUF2, w1t, b1, w2t, b2, cnt, toks, gwf, BUF1);
  ln_kernel<<<NTOK, 256, 0, stream>>>(BUF1, ln3g, ln3b, out, nullptr);
}